// Round 1
// baseline (1258.727 us; speedup 1.0000x reference)
//
#include <hip/hip_runtime.h>
#include <hip/hip_bf16.h>
#include <stdint.h>

// Problem constants
#define NN 50000            // nodes
#define RR 33               // relations
#define EE 3200000          // edges
#define DD 1600             // emb dim
#define WSZ 16              // weights_size
#define CC 10               // classes
#define NC (RR*WSZ)         // 528 columns of H
#define NCP 640             // Bt padded rows

// Bucketed-scatter params
#define NBK 64              // bucket slots (49 used)
#define BSH 10              // bucket = s >> 10  (1024 nodes/bucket)
#define NBUSED ((NN + (1<<BSH) - 1) >> BSH)   // 49
#define MEDG 4096           // edges staged per block in pass A

typedef __attribute__((ext_vector_type(8))) short bfrag;   // 8 bf16 = 4 VGPRs
typedef __attribute__((ext_vector_type(4))) float f32x4;

__device__ __forceinline__ unsigned short f2bf(float f) {
  union { float f; unsigned u; } v; v.f = f;
  unsigned r = v.u + 0x7FFF + ((v.u >> 16) & 1);   // RNE, inputs are finite
  return (unsigned short)(r >> 16);
}
__device__ __forceinline__ float bf2f(unsigned short h) {
  union { unsigned u; float f; } v; v.u = ((unsigned)h) << 16;
  return v.f;
}
// pack two fp32 -> two bf16 (round-to-nearest via +0x8000 bias; ~1 ulp max)
__device__ __forceinline__ unsigned pack2bf(float a, float b) {
  unsigned ua = __float_as_uint(a) + 0x8000u;
  unsigned ub = __float_as_uint(b) + 0x8000u;
  return (ua >> 16) | (ub & 0xFFFF0000u);
}

// ---------------- 1) fused: build B^T bf16 + edge_s histogram -----------------
__global__ __launch_bounds__(256) void k_bt_hist(const float* __restrict__ w1,
                                                 __hip_bfloat16* __restrict__ bt,
                                                 const int* __restrict__ es,
                                                 int* __restrict__ counts) {
  int b = blockIdx.x;
  if (b < 4000) {
    int idx = b * 256 + threadIdx.x;                   // NCP*DD = 1,024,000 exact
    int n = idx / DD, k = idx - n * DD;
    float v = 0.f;
    if (n < NC) {
      int r = n >> 4, o = n & 15;
      v = w1[((size_t)r * DD + k) * WSZ + o];
    }
    *reinterpret_cast<unsigned short*>(&bt[idx]) = f2bf(v);
  } else {
    int i = (b - 4000) * 256 + threadIdx.x;            // EE exact
    atomicAdd(&counts[es[i]], 1);
  }
}

// ---------------- 3b-i) per-1024-chunk partial sums (coalesced) ---------------
__global__ __launch_bounds__(256) void k_part(const int* __restrict__ counts,
                                              int* __restrict__ part) {
  int b = blockIdx.x, t = threadIdx.x;                 // NBUSED blocks
  int base = b << BSH;
  int s = 0;
  for (int j = t; j < (1 << BSH); j += 256) {
    int i = base + j; if (i < NN) s += counts[i];
  }
#pragma unroll
  for (int off = 32; off; off >>= 1) s += __shfl_down(s, off, 64);
  __shared__ int ws[4];
  if ((t & 63) == 0) ws[t >> 6] = s;
  __syncthreads();
  if (t == 0) part[b] = ws[0] + ws[1] + ws[2] + ws[3];
}

// ---------------- 3b-ii) scan 49 partials (one wave) --------------------------
__global__ __launch_bounds__(64) void k_scan2(const int* __restrict__ part,
                                              int* __restrict__ bbase,
                                              int* __restrict__ bptr,
                                              int* __restrict__ offs) {
  int t = threadIdx.x;
  int v = (t < NBUSED) ? part[t] : 0;
  int incl = v;
#pragma unroll
  for (int off = 1; off < 64; off <<= 1) {
    int x = __shfl_up(incl, off, 64);
    if (t >= off) incl += x;
  }
  int excl = incl - v;
  if (t < NBUSED) { bbase[t] = excl; bptr[t] = excl; }
  else if (t < NBK) bptr[t] = EE;
  if (t == 63) offs[NN] = EE;                          // all edges counted
}

// ---------------- 3b-iii) per-chunk exclusive scan -> offs/ptr ----------------
__global__ __launch_bounds__(1024) void k_offs(const int* __restrict__ counts,
                                               const int* __restrict__ bbase,
                                               int* __restrict__ offs,
                                               int* __restrict__ ptr) {
  __shared__ int sc[1024];
  int b = blockIdx.x, t = threadIdx.x;                 // NBUSED blocks x 1024
  int node = (b << BSH) + t;
  int v = (node < NN) ? counts[node] : 0;
  sc[t] = v;
  __syncthreads();
  for (int off = 1; off < 1024; off <<= 1) {
    int x = (t >= off) ? sc[t - off] : 0;
    __syncthreads();
    sc[t] += x;
    __syncthreads();
  }
  int excl = sc[t] - v + bbase[b];
  if (node < NN) { offs[node] = excl; ptr[node] = excl; }
}

// ---------------- 3c pass A) LDS-staged bucket binning ------------------------
__global__ __launch_bounds__(256) void k_bucket(const int* __restrict__ es,
                                                const int* __restrict__ ep,
                                                const int* __restrict__ eo,
                                                const float* __restrict__ ev,
                                                int* __restrict__ bptr,
                                                uint2* __restrict__ tmp) {
  __shared__ int lhist[NBK];
  __shared__ int lofs[NBK];
  __shared__ int lcur[NBK];
  __shared__ int lbase[NBK];
  __shared__ uint2 stage[MEDG];
  __shared__ unsigned char sbk[MEDG];
  int tid = threadIdx.x;
  int e0 = blockIdx.x * MEDG;
  int n = EE - e0; if (n > MEDG) n = MEDG;
  for (int i = tid; i < NBK; i += 256) lhist[i] = 0;
  __syncthreads();
  for (int i = tid; i < n; i += 256)
    atomicAdd(&lhist[es[e0 + i] >> BSH], 1);
  __syncthreads();
  if (tid == 0) {
    int run = 0;
    for (int b = 0; b < NBK; ++b) { lofs[b] = run; run += lhist[b]; }
  }
  __syncthreads();
  if (tid < NBK) {
    lcur[tid] = lofs[tid];
    lbase[tid] = lhist[tid] ? atomicAdd(&bptr[tid], lhist[tid]) : 0;
  }
  __syncthreads();
  for (int i = tid; i < n; i += 256) {
    int s = es[e0 + i];
    int b = s >> BSH;
    int pos = atomicAdd(&lcur[b], 1);
    uint2 r;
    r.x = (unsigned)eo[e0 + i] | ((unsigned)ep[e0 + i] << 16)
        | ((unsigned)(s & 1023) << 22);
    r.y = __float_as_uint(ev[e0 + i]);
    stage[pos] = r;
    sbk[pos] = (unsigned char)b;
  }
  __syncthreads();
  for (int i = tid; i < n; i += 256) {                 // grouped -> ~sequential writes
    int b = sbk[i];
    tmp[lbase[b] + (i - lofs[b])] = stage[i];
  }
}

// ---------------- 3c pass B) within-bucket CSR scatter (L2-resident) ----------
#define SBPB 8               // sub-blocks per bucket
__global__ __launch_bounds__(256) void k_scatter2(const uint2* __restrict__ tmp,
                                                  const int* __restrict__ offs,
                                                  int* __restrict__ ptr,
                                                  uint2* __restrict__ recs) {
  int b = blockIdx.x;                                  // NBUSED x SBPB grid
  int n0 = b << BSH, n1 = (b + 1) << BSH;
  if (n1 > NN) n1 = NN;
  int start = offs[n0], endv = offs[n1];
  int tid = blockIdx.y * 256 + (int)threadIdx.x;
  for (int i = start + tid; i < endv; i += SBPB * 256) {
    uint2 r = tmp[i];
    int s = n0 + (int)(r.x >> 22);
    int pos = atomicAdd(&ptr[s], 1);
    recs[pos] = r;                                     // random within ~512KB: L2 absorbs
  }
}

// ---------------- 4) GEMM: Hb = emb(fp32, fused convert) @ B, bf16 out --------
// NNT=4 (orphan cols 512-527 folded into nt==0 via Bx) + 3-deep A prefetch.
#define BM 128
#define BN 128
#define BK 32
#define NMT 391              // m-tiles
#define NNT 4                // n-tiles of 128; cols 512..527 via Bx in nt==0
#define MPX 49               // m-strips per XCD (8*49 >= 391)
#define KIT (DD / BK)        // 50 K-iterations

// fine barrier: drain LDS + the oldest vm ops (the B DMAs); leave the 8
// newest A prefetch loads (2 iterations deep) in flight across the barrier.
#define BAR_FINE() asm volatile("s_waitcnt vmcnt(8) lgkmcnt(0)\n\ts_barrier" ::: "memory")

// slot-literal A staging (runtime slot index would spill va[] to scratch)
#define LOADA(K0, S) { \
  _Pragma("unroll") for (int j = 0; j < 2; ++j) { \
    const float4* gp = (const float4*)(A + rowAg[j] + (K0) + kcA[j]); \
    va[S][j][0] = gp[0]; va[S][j][1] = gp[1]; } }

#define PACKA(S, DST) { \
  _Pragma("unroll") for (int j = 0; j < 2; ++j) { \
    uint4 w; \
    w.x = pack2bf(va[S][j][0].x, va[S][j][0].y); \
    w.y = pack2bf(va[S][j][0].z, va[S][j][0].w); \
    w.z = pack2bf(va[S][j][1].x, va[S][j][1].y); \
    w.w = pack2bf(va[S][j][1].z, va[S][j][1].w); \
    *reinterpret_cast<uint4*>((DST) + wofsA[j]) = w; } }

// one steady-state K-iteration; SI = IT%3 (issue slot), SC = (IT+1)%3 (consume)
#define GITER(IT, SI, SC) { \
  int buf_ = (IT) & 1, nbuf_ = buf_ ^ 1; \
  dmaB(((IT) + 1) * BK, nbuf_); \
  __builtin_amdgcn_sched_barrier(0); \
  LOADA(((IT) + 3) * BK, SI); \
  mfmaTile(As[buf_], Bs[buf_], Bx[buf_]); \
  PACKA(SC, As[nbuf_]); \
  BAR_FINE(); }

__global__ __launch_bounds__(256) void k_gemm(const float* __restrict__ A,
                                              const __hip_bfloat16* __restrict__ Bt,
                                              __hip_bfloat16* __restrict__ Hb) {
  __shared__ __align__(16) __hip_bfloat16 As[2][BM * BK];   // 8 KB each
  __shared__ __align__(16) __hip_bfloat16 Bs[2][BN * BK];   // 8 KB each
  __shared__ __align__(16) __hip_bfloat16 Bx[2][16 * BK];   // 1 KB each (orphan cols)
  int tid  = threadIdx.x;
  int wave = tid >> 6, lane = tid & 63;

  // XCD-aware swizzle: L%8 = XCD; per XCD a contiguous band of m-strips,
  // 4 n-tiles of a strip adjacent -> A strip served by ONE L2.
  int L = blockIdx.x;
  int xcd = L & 7;
  int r = L >> 3;
  int lm = r >> 2, nt = r & 3;
  int mt = xcd * MPX + lm;
  if (mt >= NMT) return;                // 4 no-op blocks (before any barrier)
  int m0 = mt * BM, n0 = nt * BN;

  int wm = (wave >> 1) * 64, wn = (wave & 1) * 64;       // 2x2 wave quadrants
  int ld = lane & 15, quad = lane >> 4;

  bool bxs  = (nt == 0);                // this block stages/computes cols 512-527
  bool act5 = bxs && (wn == 64);        // waves carrying the 5th B fragment

  // ---- staging thread roles ----
  size_t rowAg[2];  int kcA[2];  int wofsA[2];           // A: load + swizzled LDS write
  size_t srcB[2];                                        // B: swizzled DMA source
#pragma unroll
  for (int j = 0; j < 2; ++j) {
    int idx = j * 256 + tid;
    int lrow = idx >> 2, kq = idx & 3;
    kcA[j] = kq * 8;
    int grow = m0 + lrow; if (grow > NN - 1) grow = NN - 1;
    rowAg[j] = (size_t)grow * DD;
    wofsA[j] = lrow * BK + ((kq + ((lrow >> 1) & 3)) & 3) * 8;   // XOR chunk swizzle
    int lcol = idx >> 2, pc = idx & 3;
    int kqsrc = (pc - ((lcol >> 1) & 3)) & 3;            // inverse swizzle on source
    srcB[j] = (size_t)(n0 + lcol) * DD + kqsrc * 8;
  }
  size_t srcBx = (size_t)(512 + (tid >> 2)) * DD + (size_t)(tid & 3) * 8;  // tid<64 only
  // fragment read offsets (swizzle term is mi/ni-invariant: (x+16)>>1 = x>>1+8)
  int swA = ((wm + ld) >> 1) & 3;
  int swB = ((wn + ld) >> 1) & 3;
  int rchA = ((quad + swA) & 3) * 8;
  int rchB = ((quad + swB) & 3) * 8;

  auto dmaB = [&](int k0, int buf) {
#pragma unroll
    for (int j = 0; j < 2; ++j) {
      const __hip_bfloat16* gp = Bt + srcB[j] + k0;
      __builtin_amdgcn_global_load_lds(
          (const __attribute__((address_space(1))) void*)gp,
          (__attribute__((address_space(3))) void*)(Bs[buf] + ((size_t)j * 256 + tid) * 8),
          16, 0, 0);
    }
    if (bxs && tid < 64) {                               // wave 0, uniform exec
      const __hip_bfloat16* gp = Bt + srcBx + k0;
      __builtin_amdgcn_global_load_lds(
          (const __attribute__((address_space(1))) void*)gp,
          (__attribute__((address_space(3))) void*)(Bx[buf] + tid * 8),
          16, 0, 0);
    }
  };

  float4 va[3][2][2];                                    // 3-deep A prefetch

  f32x4 acc[4][5] = {};
  auto mfmaTile = [&](const __hip_bfloat16* as, const __hip_bfloat16* bs,
                      const __hip_bfloat16* bx) {
    bfrag af[4], bf[5];
#pragma unroll
    for (int mi = 0; mi < 4; ++mi)
      af[mi] = *(const bfrag*)(as + (wm + mi * 16 + ld) * BK + rchA);
#pragma unroll
    for (int ni = 0; ni < 4; ++ni)
      bf[ni] = *(const bfrag*)(bs + (wn + ni * 16 + ld) * BK + rchB);
    if (act5) bf[4] = *(const bfrag*)(bx + ld * BK + quad * 8);
#pragma unroll
    for (int mi = 0; mi < 4; ++mi) {
#pragma unroll
      for (int ni = 0; ni < 4; ++ni)
        acc[mi][ni] = __builtin_amdgcn_mfma_f32_16x16x32_bf16(af[mi], bf[ni],
                                                              acc[mi][ni], 0, 0, 0);
      if (act5)
        acc[mi][4] = __builtin_amdgcn_mfma_f32_16x16x32_bf16(af[mi], bf[4],
                                                             acc[mi][4], 0, 0, 0);
    }
  };

  // ---- prologue: step0 staged, steps 1-2 in regs (slot = step % 3) ----
  LOADA(0, 0);
  dmaB(0, 0);
  __builtin_amdgcn_sched_barrier(0);
  PACKA(0, As[0]);
  LOADA(BK, 1);
  LOADA(2 * BK, 2);
  BAR_FINE();

  // ---- main loop: it = 0..46, slots rotate with period 3 ----
  for (int it = 0; it < 45; it += 3) {
    GITER(it,     0, 1);
    GITER(it + 1, 1, 2);
    GITER(it + 2, 2, 0);
  }
  GITER(45, 0, 1);
  GITER(46, 1, 2);
  // ---- it = 47: no A issue ----
  {
    dmaB(48 * BK, 0);
    mfmaTile(As[1], Bs[1], Bx[1]);
    PACKA(0, As[0]);                     // step 48 (loaded at it=45)
    __syncthreads();
  }
  // ---- it = 48 ----
  {
    dmaB(49 * BK, 1);
    mfmaTile(As[0], Bs[0], Bx[0]);
    PACKA(1, As[1]);                     // step 49 (loaded at it=46)
    __syncthreads();
  }
  // ---- it = 49: compute only ----
  mfmaTile(As[1], Bs[1], Bx[1]);

  // ---- epilogue ----
#pragma unroll
  for (int mi = 0; mi < 4; ++mi) {
#pragma unroll
    for (int ni = 0; ni < 4; ++ni) {
      int col = n0 + wn + ni * 16 + ld;                  // always < 528 with NNT=4
#pragma unroll
      for (int r2 = 0; r2 < 4; ++r2) {
        int row = m0 + wm + mi * 16 + quad * 4 + r2;     // C/D: col=lane&15, row=quad*4+reg
        if (row < NN)
          *reinterpret_cast<unsigned short*>(&Hb[(size_t)row * NC + col]) =
              f2bf(acc[mi][ni][r2]);
      }
    }
    if (act5) {
      int col = 512 + ld;
#pragma unroll
      for (int r2 = 0; r2 < 4; ++r2) {
        int row = m0 + wm + mi * 16 + quad * 4 + r2;
        if (row < NN)
          *reinterpret_cast<unsigned short*>(&Hb[(size_t)row * NC + col]) =
              f2bf(acc[mi][4][r2]);
      }
    }
  }
}

// ---------------- 5) layer-1 aggregation: one wave per destination node -------
__global__ __launch_bounds__(256) void k_agg1(const uint2* __restrict__ recs,
                                              const int* __restrict__ offs,
                                              const __hip_bfloat16* __restrict__ Hb,
                                              const float* __restrict__ bias1,
                                              float* __restrict__ h1) {
  int wid  = (blockIdx.x * 256 + threadIdx.x) >> 6;      // exactly NN waves
  int lane = threadIdx.x & 63;
  int grp = lane >> 4, c = lane & 15;
  int beg = offs[wid], end = offs[wid + 1];
  float acc = 0.f;
  int e = beg + grp;
  for (; e + 4 < end; e += 8) {                          // 2x unroll: 2 chains in flight
    uint2 r0 = recs[e];
    uint2 r1 = recs[e + 4];
    int o0 = r0.x & 0xFFFF, p0 = (r0.x >> 16) & 0x3F;
    int o1 = r1.x & 0xFFFF, p1 = (r1.x >> 16) & 0x3F;
    unsigned short h0 = *reinterpret_cast<const unsigned short*>(
        &Hb[(size_t)o0 * NC + p0 * WSZ + c]);
    unsigned short h1v = *reinterpret_cast<const unsigned short*>(
        &Hb[(size_t)o1 * NC + p1 * WSZ + c]);
    acc += __uint_as_float(r0.y) * bf2f(h0);
    acc += __uint_as_float(r1.y) * bf2f(h1v);
  }
  if (e < end) {
    uint2 r = recs[e];
    int o = r.x & 0xFFFF, p = (r.x >> 16) & 0x3F;
    unsigned short h = *reinterpret_cast<const unsigned short*>(
        &Hb[(size_t)o * NC + p * WSZ + c]);
    acc += __uint_as_float(r.y) * bf2f(h);
  }
  acc += __shfl_xor(acc, 16, 64);
  acc += __shfl_xor(acc, 32, 64);
  if (lane < 16) h1[wid * WSZ + c] = fmaxf(acc + bias1[c], 0.f);
}

// ---------------- 6) fused layer-2 projection + aggregation -------------------
// out[s,c] = b2[c] + sum_e val * sum_i h1[o,i] * w2[p,i,c]
// h1 is 3.2 MB -> L2-resident gathers (vs 52.8 MB H2 from L3); H2 eliminated.
__global__ __launch_bounds__(256) void k_agg2f(const uint2* __restrict__ recs,
                                               const int* __restrict__ offs,
                                               const float* __restrict__ h1,
                                               const float* __restrict__ w2,
                                               const float* __restrict__ bias2,
                                               float* __restrict__ out) {
  __shared__ float w2s[RR * WSZ * 12];                   // stride 12: b128-aligned rows
  for (int i = threadIdx.x; i < RR * WSZ * CC; i += 256) {
    int pi = i / CC, c = i - pi * CC;
    w2s[pi * 12 + c] = w2[i];
  }
  __syncthreads();
  int wid  = (blockIdx.x * 256 + threadIdx.x) >> 6;      // exactly NN waves
  int lane = threadIdx.x & 63;
  int grp = lane >> 4, i16 = lane & 15;                  // lane owns i = i16
  int beg = offs[wid], end = offs[wid + 1];
  float t[CC] = {};
  int e = beg + grp;
  for (; e + 4 < end; e += 8) {                          // 2 chains in flight
    uint2 r0 = recs[e];
    uint2 r1 = recs[e + 4];
    int o0 = r0.x & 0xFFFF, p0 = (r0.x >> 16) & 0x3F;
    int o1 = r1.x & 0xFFFF, p1 = (r1.x >> 16) & 0x3F;
    float x0 = __uint_as_float(r0.y) * h1[o0 * WSZ + i16];   // 64B/group, L2-hit
    float x1 = __uint_as_float(r1.y) * h1[o1 * WSZ + i16];
    const float* wp0 = w2s + (p0 * WSZ + i16) * 12;
    const float* wp1 = w2s + (p1 * WSZ + i16) * 12;
#pragma unroll
    for (int c = 0; c < CC; ++c) t[c] += x0 * wp0[c] + x1 * wp1[c];
  }
  if (e < end) {
    uint2 r = recs[e];
    int o = r.x & 0xFFFF, p = (r.x >> 16) & 0x3F;
    float x = __uint_as_float(r.y) * h1[o * WSZ + i16];
    const float* wp = w2s + (p * WSZ + i16) * 12;
#pragma unroll
    for (int c = 0; c < CC; ++c) t[c] += x * wp[c];
  }
  // reduce over all 64 lanes (16 i-partials x 4 groups) per class
#pragma unroll
  for (int c = 0; c < CC; ++c) {
    float v = t[c];
    v += __shfl_xor(v, 1, 64);
    v += __shfl_xor(v, 2, 64);
    v += __shfl_xor(v, 4, 64);
    v += __shfl_xor(v, 8, 64);
    v += __shfl_xor(v, 16, 64);
    v += __shfl_xor(v, 32, 64);
    t[c] = v;
  }
  if (lane == 0) {
#pragma unroll
    for (int c = 0; c < CC; ++c) out[wid * CC + c] = t[c] + bias2[c];
  }
}

// ---------------- launcher ----------------
extern "C" void kernel_launch(void* const* d_in, const int* in_sizes, int n_in,
                              void* d_out, int out_size, void* d_ws, size_t ws_size,
                              hipStream_t stream) {
  const float* emb = (const float*)d_in[0];
  const float* w1  = (const float*)d_in[1];
  const float* b1  = (const float*)d_in[2];
  const float* w2  = (const float*)d_in[3];
  const float* b2  = (const float*)d_in[4];
  const float* ev  = (const float*)d_in[5];
  const int*   es  = (const int*)d_in[6];
  const int*   ep  = (const int*)d_in[7];
  const int*   eo  = (const int*)d_in[8];
  float* out = (float*)d_out;

  char* ws = (char*)d_ws;
  size_t off = 0;
  auto alloc = [&](size_t bytes) -> void* {
    void* p = ws + off;
    off = (off + bytes + 255) & ~(size_t)255;
    return p;
  };
  __hip_bfloat16* Bt  = (__hip_bfloat16*)alloc((size_t)NCP * DD * 2);  //   2 MB
  __hip_bfloat16* Hb  = (__hip_bfloat16*)alloc((size_t)NN * NC * 2);   // 52.8 MB
  float* h1   = (float*)alloc((size_t)NN * WSZ * 4);                   //  3.2 MB
  uint2* recs = (uint2*)alloc((size_t)EE * 8);                         // 25.6 MB
  int* counts = (int*)alloc((size_t)NN * 4);
  int* offs   = (int*)alloc((size_t)(NN + 1) * 4);
  int* ptr    = (int*)alloc((size_t)(NN + 1) * 4);
  int* bptr   = (int*)alloc((size_t)NBK * 4);
  int* part   = (int*)alloc((size_t)NBUSED * 4);
  int* bbase  = (int*)alloc((size_t)NBUSED * 4);
  // tmp aliases Hb (dead until k_gemm)
  uint2* tmp = (uint2*)Hb;

  hipMemsetAsync(counts, 0, (size_t)NN * 4, stream);

  k_bt_hist <<<16500, 256, 0, stream>>>(w1, Bt, es, counts);
  k_part    <<<NBUSED, 256, 0, stream>>>(counts, part);
  k_scan2   <<<1,      64, 0, stream>>>(part, bbase, bptr, offs);
  k_offs    <<<NBUSED,1024, 0, stream>>>(counts, bbase, offs, ptr);
  k_bucket  <<<(EE + MEDG - 1) / MEDG, 256, 0, stream>>>(es, ep, eo, ev, bptr, tmp);
  dim3 sg(NBUSED, SBPB);
  k_scatter2<<<sg,    256, 0, stream>>>(tmp, offs, ptr, recs);
  k_gemm    <<<8 * MPX * NNT, 256, 0, stream>>>(emb, Bt, Hb);   // 1568 blocks
  k_agg1    <<<12500, 256, 0, stream>>>(recs, offs, Hb, b1, h1);
  k_agg2f   <<<12500, 256, 0, stream>>>(recs, offs, h1, w2, b2, out);
}

// Round 2
// 1044.806 us; speedup vs baseline: 1.2047x; 1.2047x over previous
//
#include <hip/hip_runtime.h>
#include <hip/hip_bf16.h>
#include <stdint.h>

// Problem constants
#define NN 50000            // nodes
#define RR 33               // relations
#define EE 3200000          // edges
#define DD 1600             // emb dim
#define WSZ 16              // weights_size
#define CC 10               // classes
#define NC (RR*WSZ)         // 528 columns of H
#define NCP 640             // Bt padded rows (5 * 128 column tiles)

// Bucketed-scatter params
#define NBK 64              // bucket slots (49 used)
#define BSH 10              // bucket = s >> 10  (1024 nodes/bucket)
#define NBUSED ((NN + (1<<BSH) - 1) >> BSH)   // 49
#define MEDG 4096           // edges staged per block in pass A

typedef __attribute__((ext_vector_type(8))) short bfrag;   // 8 bf16 = 4 VGPRs
typedef __attribute__((ext_vector_type(4))) float f32x4;

__device__ __forceinline__ unsigned short f2bf(float f) {
  union { float f; unsigned u; } v; v.f = f;
  unsigned r = v.u + 0x7FFF + ((v.u >> 16) & 1);   // RNE, inputs are finite
  return (unsigned short)(r >> 16);
}
__device__ __forceinline__ float bf2f(unsigned short h) {
  union { unsigned u; float f; } v; v.u = ((unsigned)h) << 16;
  return v.f;
}
// pack two fp32 -> two bf16 (round-to-nearest via +0x8000 bias; ~1 ulp max)
__device__ __forceinline__ unsigned pack2bf(float a, float b) {
  unsigned ua = __float_as_uint(a) + 0x8000u;
  unsigned ub = __float_as_uint(b) + 0x8000u;
  return (ua >> 16) | (ub & 0xFFFF0000u);
}

// ---------------- 1) fused: build B^T bf16 + edge_s histogram -----------------
__global__ __launch_bounds__(256) void k_bt_hist(const float* __restrict__ w1,
                                                 __hip_bfloat16* __restrict__ bt,
                                                 const int* __restrict__ es,
                                                 int* __restrict__ counts) {
  int b = blockIdx.x;
  if (b < 4000) {
    int idx = b * 256 + threadIdx.x;                   // NCP*DD = 1,024,000 exact
    int n = idx / DD, k = idx - n * DD;
    float v = 0.f;
    if (n < NC) {
      int r = n >> 4, o = n & 15;
      v = w1[((size_t)r * DD + k) * WSZ + o];
    }
    *reinterpret_cast<unsigned short*>(&bt[idx]) = f2bf(v);
  } else {
    int i = (b - 4000) * 256 + threadIdx.x;            // EE exact
    atomicAdd(&counts[es[i]], 1);
  }
}

// ---------------- 3b-i) per-1024-chunk partial sums (coalesced) ---------------
__global__ __launch_bounds__(256) void k_part(const int* __restrict__ counts,
                                              int* __restrict__ part) {
  int b = blockIdx.x, t = threadIdx.x;                 // NBUSED blocks
  int base = b << BSH;
  int s = 0;
  for (int j = t; j < (1 << BSH); j += 256) {
    int i = base + j; if (i < NN) s += counts[i];
  }
#pragma unroll
  for (int off = 32; off; off >>= 1) s += __shfl_down(s, off, 64);
  __shared__ int ws[4];
  if ((t & 63) == 0) ws[t >> 6] = s;
  __syncthreads();
  if (t == 0) part[b] = ws[0] + ws[1] + ws[2] + ws[3];
}

// ---------------- 3b-ii) scan 49 partials (one wave) --------------------------
__global__ __launch_bounds__(64) void k_scan2(const int* __restrict__ part,
                                              int* __restrict__ bbase,
                                              int* __restrict__ bptr,
                                              int* __restrict__ offs) {
  int t = threadIdx.x;
  int v = (t < NBUSED) ? part[t] : 0;
  int incl = v;
#pragma unroll
  for (int off = 1; off < 64; off <<= 1) {
    int x = __shfl_up(incl, off, 64);
    if (t >= off) incl += x;
  }
  int excl = incl - v;
  if (t < NBUSED) { bbase[t] = excl; bptr[t] = excl; }
  else if (t < NBK) bptr[t] = EE;
  if (t == 63) offs[NN] = EE;                          // all edges counted
}

// ---------------- 3b-iii) per-chunk exclusive scan -> offs/ptr ----------------
__global__ __launch_bounds__(1024) void k_offs(const int* __restrict__ counts,
                                               const int* __restrict__ bbase,
                                               int* __restrict__ offs,
                                               int* __restrict__ ptr) {
  __shared__ int sc[1024];
  int b = blockIdx.x, t = threadIdx.x;                 // NBUSED blocks x 1024
  int node = (b << BSH) + t;
  int v = (node < NN) ? counts[node] : 0;
  sc[t] = v;
  __syncthreads();
  for (int off = 1; off < 1024; off <<= 1) {
    int x = (t >= off) ? sc[t - off] : 0;
    __syncthreads();
    sc[t] += x;
    __syncthreads();
  }
  int excl = sc[t] - v + bbase[b];
  if (node < NN) { offs[node] = excl; ptr[node] = excl; }
}

// ---------------- 3c pass A) LDS-staged bucket binning ------------------------
__global__ __launch_bounds__(256) void k_bucket(const int* __restrict__ es,
                                                const int* __restrict__ ep,
                                                const int* __restrict__ eo,
                                                const float* __restrict__ ev,
                                                int* __restrict__ bptr,
                                                uint2* __restrict__ tmp) {
  __shared__ int lhist[NBK];
  __shared__ int lofs[NBK];
  __shared__ int lcur[NBK];
  __shared__ int lbase[NBK];
  __shared__ uint2 stage[MEDG];
  __shared__ unsigned char sbk[MEDG];
  int tid = threadIdx.x;
  int e0 = blockIdx.x * MEDG;
  int n = EE - e0; if (n > MEDG) n = MEDG;
  for (int i = tid; i < NBK; i += 256) lhist[i] = 0;
  __syncthreads();
  for (int i = tid; i < n; i += 256)
    atomicAdd(&lhist[es[e0 + i] >> BSH], 1);
  __syncthreads();
  if (tid == 0) {
    int run = 0;
    for (int b = 0; b < NBK; ++b) { lofs[b] = run; run += lhist[b]; }
  }
  __syncthreads();
  if (tid < NBK) {
    lcur[tid] = lofs[tid];
    lbase[tid] = lhist[tid] ? atomicAdd(&bptr[tid], lhist[tid]) : 0;
  }
  __syncthreads();
  for (int i = tid; i < n; i += 256) {
    int s = es[e0 + i];
    int b = s >> BSH;
    int pos = atomicAdd(&lcur[b], 1);
    uint2 r;
    r.x = (unsigned)eo[e0 + i] | ((unsigned)ep[e0 + i] << 16)
        | ((unsigned)(s & 1023) << 22);
    r.y = __float_as_uint(ev[e0 + i]);
    stage[pos] = r;
    sbk[pos] = (unsigned char)b;
  }
  __syncthreads();
  for (int i = tid; i < n; i += 256) {                 // grouped -> ~sequential writes
    int b = sbk[i];
    tmp[lbase[b] + (i - lofs[b])] = stage[i];
  }
}

// ---------------- 3c pass B) within-bucket CSR scatter (L2-resident) ----------
#define SBPB 8               // sub-blocks per bucket
__global__ __launch_bounds__(256) void k_scatter2(const uint2* __restrict__ tmp,
                                                  const int* __restrict__ offs,
                                                  int* __restrict__ ptr,
                                                  uint2* __restrict__ recs) {
  int b = blockIdx.x;                                  // NBUSED x SBPB grid
  int n0 = b << BSH, n1 = (b + 1) << BSH;
  if (n1 > NN) n1 = NN;
  int start = offs[n0], endv = offs[n1];
  int tid = blockIdx.y * 256 + (int)threadIdx.x;
  for (int i = start + tid; i < endv; i += SBPB * 256) {
    uint2 r = tmp[i];
    int s = n0 + (int)(r.x >> 22);
    int pos = atomicAdd(&ptr[s], 1);
    recs[pos] = r;                                     // random within ~512KB: L2 absorbs
  }
}

// ---------------- 4) GEMM: Hb = emb(fp32, fused convert) @ B, bf16 out --------
// Round-0 structure (measured 84 VGPR / 30% occ / ~220us): XCD swizzle +
// bank-swizzled LDS + 2-deep A prefetch crossing raw s_barrier. NNT=5.
#define BM 128
#define BN 128
#define BK 32
#define NMT 391              // m-tiles
#define NNT 5                // n-tiles
#define MPX 49               // m-strips per XCD (8*49 >= 391)
#define KIT (DD / BK)        // 50 K-iterations

// fine barrier: drain LDS + the 2 oldest vm ops (the B DMAs); leave the 8
// newer A prefetch loads in flight across the barrier.
#define BAR_FINE() asm volatile("s_waitcnt vmcnt(8) lgkmcnt(0)\n\ts_barrier" ::: "memory")

__global__ __launch_bounds__(256) void k_gemm(const float* __restrict__ A,
                                              const __hip_bfloat16* __restrict__ Bt,
                                              __hip_bfloat16* __restrict__ Hb) {
  __shared__ __align__(16) __hip_bfloat16 As[2][BM * BK];   // 8 KB each
  __shared__ __align__(16) __hip_bfloat16 Bs[2][BN * BK];   // 8 KB each
  int tid  = threadIdx.x;
  int wave = tid >> 6, lane = tid & 63;

  // XCD-aware swizzle: L%8 = XCD; per XCD a contiguous band of m-strips,
  // 5 n-tiles of a strip adjacent -> A strip served by ONE L2.
  int L = blockIdx.x;
  int xcd = L & 7;
  int r = L >> 3;
  int lm = r / NNT, nt = r - lm * NNT;
  int mt = xcd * MPX + lm;
  if (mt >= NMT) return;                // 5 no-op blocks (before any barrier)
  int m0 = mt * BM, n0 = nt * BN;

  int wm = (wave >> 1) * 64, wn = (wave & 1) * 64;       // 2x2 wave quadrants
  int ld = lane & 15, quad = lane >> 4;

  bool nact[4];
#pragma unroll
  for (int ni = 0; ni < 4; ++ni) nact[ni] = (n0 + wn + ni * 16) < NC;

  // ---- staging thread roles ----
  size_t rowAg[2];  int kcA[2];  int wofsA[2];           // A: load + swizzled LDS write
  size_t srcB[2];                                        // B: swizzled DMA source
#pragma unroll
  for (int j = 0; j < 2; ++j) {
    int idx = j * 256 + tid;
    int lrow = idx >> 2, kq = idx & 3;
    kcA[j] = kq * 8;
    int grow = m0 + lrow; if (grow > NN - 1) grow = NN - 1;
    rowAg[j] = (size_t)grow * DD;
    wofsA[j] = lrow * BK + ((kq + ((lrow >> 1) & 3)) & 3) * 8;   // XOR chunk swizzle
    int lcol = idx >> 2, pc = idx & 3;
    int kqsrc = (pc - ((lcol >> 1) & 3)) & 3;            // inverse swizzle on source
    srcB[j] = (size_t)(n0 + lcol) * DD + kqsrc * 8;
  }
  // fragment read offsets (swizzle term is mi/ni-invariant: (x+16)>>1 = x>>1+8)
  int swA = ((wm + ld) >> 1) & 3;
  int swB = ((wn + ld) >> 1) & 3;
  int rchA = ((quad + swA) & 3) * 8;
  int rchB = ((quad + swB) & 3) * 8;

  auto dmaB = [&](int k0, __hip_bfloat16* dst) {
#pragma unroll
    for (int j = 0; j < 2; ++j) {
      const __hip_bfloat16* gp = Bt + srcB[j] + k0;
      __builtin_amdgcn_global_load_lds(
          (const __attribute__((address_space(1))) void*)gp,
          (__attribute__((address_space(3))) void*)(dst + ((size_t)j * 256 + tid) * 8),
          16, 0, 0);
    }
  };
  float4 va[2][2][2];
  auto loadA = [&](int k0, int slot) {
#pragma unroll
    for (int j = 0; j < 2; ++j) {
      const float4* gp = (const float4*)(A + rowAg[j] + k0 + kcA[j]);
      va[slot][j][0] = gp[0]; va[slot][j][1] = gp[1];
    }
  };
  auto packA = [&](int slot, __hip_bfloat16* dst) {
#pragma unroll
    for (int j = 0; j < 2; ++j) {
      uint4 w;
      w.x = pack2bf(va[slot][j][0].x, va[slot][j][0].y);
      w.y = pack2bf(va[slot][j][0].z, va[slot][j][0].w);
      w.z = pack2bf(va[slot][j][1].x, va[slot][j][1].y);
      w.w = pack2bf(va[slot][j][1].z, va[slot][j][1].w);
      *reinterpret_cast<uint4*>(dst + wofsA[j]) = w;
    }
  };

  f32x4 acc[4][4] = {};
  auto mfmaTile = [&](const __hip_bfloat16* as, const __hip_bfloat16* bs) {
    bfrag af[4], bf[4];
#pragma unroll
    for (int mi = 0; mi < 4; ++mi)
      af[mi] = *(const bfrag*)(as + (wm + mi * 16 + ld) * BK + rchA);
#pragma unroll
    for (int ni = 0; ni < 4; ++ni)
      if (nact[ni])
        bf[ni] = *(const bfrag*)(bs + (wn + ni * 16 + ld) * BK + rchB);
#pragma unroll
    for (int mi = 0; mi < 4; ++mi)
#pragma unroll
      for (int ni = 0; ni < 4; ++ni)
        if (nact[ni])
          acc[mi][ni] = __builtin_amdgcn_mfma_f32_16x16x32_bf16(af[mi], bf[ni],
                                                                acc[mi][ni], 0, 0, 0);
  };

  // ---- prologue: T0 staged, T1 loads in regs ----
  loadA(0, 0);
  dmaB(0, Bs[0]);
  packA(0, As[0]);
  loadA(BK, 1);
  __syncthreads();

  // ---- main loop: it = 0..KIT-3 (48 iters), full 2-deep pipeline ----
#pragma unroll 2
  for (int it = 0; it < KIT - 2; ++it) {
    int buf = it & 1, nbuf = buf ^ 1;
    int k0 = it * BK;
    dmaB(k0 + BK, Bs[nbuf]);                 // oldest vm ops this iter
    __builtin_amdgcn_sched_barrier(0);       // keep DMA before A loads in vmcnt order
    loadA(k0 + 2 * BK, buf);                 // 8 loads that CROSS the barrier
    mfmaTile(As[buf], Bs[buf]);
    packA(nbuf, As[nbuf]);                   // consumes loads issued LAST iter
    BAR_FINE();                              // vmcnt(8): B done, A prefetch in flight
  }
  // ---- it = KIT-2 (48): no A issue; full drain barrier ----
  {
    int buf = (KIT - 2) & 1, nbuf = buf ^ 1;
    dmaB((KIT - 1) * BK, Bs[nbuf]);
    mfmaTile(As[buf], Bs[buf]);
    packA(nbuf, As[nbuf]);
    __syncthreads();
  }
  // ---- it = KIT-1 (49): compute only ----
  mfmaTile(As[(KIT - 1) & 1], Bs[(KIT - 1) & 1]);

  // ---- epilogue ----
#pragma unroll
  for (int mi = 0; mi < 4; ++mi)
#pragma unroll
    for (int ni = 0; ni < 4; ++ni) {
      int col = n0 + wn + ni * 16 + ld;
      if (col >= NC) continue;
#pragma unroll
      for (int r2 = 0; r2 < 4; ++r2) {
        int row = m0 + wm + mi * 16 + quad * 4 + r2;     // C/D: col=lane&15, row=quad*4+reg
        if (row < NN)
          *reinterpret_cast<unsigned short*>(&Hb[(size_t)row * NC + col]) =
              f2bf(acc[mi][ni][r2]);
      }
    }
}

// ---------------- 5) layer-1 aggregation: one wave per destination node -------
// 4 gather chains in flight per 16-lane group (latency-bound loop, MLP x2)
__global__ __launch_bounds__(256) void k_agg1(const uint2* __restrict__ recs,
                                              const int* __restrict__ offs,
                                              const __hip_bfloat16* __restrict__ Hb,
                                              const float* __restrict__ bias1,
                                              float* __restrict__ h1) {
  int wid  = (blockIdx.x * 256 + threadIdx.x) >> 6;      // exactly NN waves
  int lane = threadIdx.x & 63;
  int grp = lane >> 4, c = lane & 15;
  int beg = offs[wid], end = offs[wid + 1];
  float acc = 0.f;
  int e = beg + grp;
  for (; e + 12 < end; e += 16) {                        // 4 independent chains
    uint2 r0 = recs[e];
    uint2 r1 = recs[e + 4];
    uint2 r2 = recs[e + 8];
    uint2 r3 = recs[e + 12];
    int o0 = r0.x & 0xFFFF, p0 = (r0.x >> 16) & 0x3F;
    int o1 = r1.x & 0xFFFF, p1 = (r1.x >> 16) & 0x3F;
    int o2 = r2.x & 0xFFFF, p2 = (r2.x >> 16) & 0x3F;
    int o3 = r3.x & 0xFFFF, p3 = (r3.x >> 16) & 0x3F;
    unsigned short h0 = *reinterpret_cast<const unsigned short*>(
        &Hb[(size_t)o0 * NC + p0 * WSZ + c]);
    unsigned short h1v = *reinterpret_cast<const unsigned short*>(
        &Hb[(size_t)o1 * NC + p1 * WSZ + c]);
    unsigned short h2v = *reinterpret_cast<const unsigned short*>(
        &Hb[(size_t)o2 * NC + p2 * WSZ + c]);
    unsigned short h3v = *reinterpret_cast<const unsigned short*>(
        &Hb[(size_t)o3 * NC + p3 * WSZ + c]);
    acc += __uint_as_float(r0.y) * bf2f(h0);
    acc += __uint_as_float(r1.y) * bf2f(h1v);
    acc += __uint_as_float(r2.y) * bf2f(h2v);
    acc += __uint_as_float(r3.y) * bf2f(h3v);
  }
  for (; e < end; e += 4) {
    uint2 r = recs[e];
    int o = r.x & 0xFFFF, p = (r.x >> 16) & 0x3F;
    unsigned short h = *reinterpret_cast<const unsigned short*>(
        &Hb[(size_t)o * NC + p * WSZ + c]);
    acc += __uint_as_float(r.y) * bf2f(h);
  }
  acc += __shfl_xor(acc, 16, 64);
  acc += __shfl_xor(acc, 32, 64);
  if (lane < 16) h1[wid * WSZ + c] = fmaxf(acc + bias1[c], 0.f);
}

// ---------------- 6) fused layer-2 projection + aggregation -------------------
// out[s,c] = b2[c] + sum_e val * sum_i h1[o,i] * w2[p,i,c]
// h1 is 3.2 MB -> L2-resident gathers; H2 never materialized.
__global__ __launch_bounds__(256) void k_agg2f(const uint2* __restrict__ recs,
                                               const int* __restrict__ offs,
                                               const float* __restrict__ h1,
                                               const float* __restrict__ w2,
                                               const float* __restrict__ bias2,
                                               float* __restrict__ out) {
  __shared__ float w2s[RR * WSZ * 12];                   // stride 12: b128-aligned rows
  for (int i = threadIdx.x; i < RR * WSZ * CC; i += 256) {
    int pi = i / CC, c = i - pi * CC;
    w2s[pi * 12 + c] = w2[i];
  }
  __syncthreads();
  int wid  = (blockIdx.x * 256 + threadIdx.x) >> 6;      // exactly NN waves
  int lane = threadIdx.x & 63;
  int grp = lane >> 4, i16 = lane & 15;                  // lane owns i = i16
  int beg = offs[wid], end = offs[wid + 1];
  float t[CC] = {};
  int e = beg + grp;
  for (; e + 12 < end; e += 16) {                        // 4 independent chains
    uint2 r0 = recs[e];
    uint2 r1 = recs[e + 4];
    uint2 r2 = recs[e + 8];
    uint2 r3 = recs[e + 12];
    int o0 = r0.x & 0xFFFF, p0 = (r0.x >> 16) & 0x3F;
    int o1 = r1.x & 0xFFFF, p1 = (r1.x >> 16) & 0x3F;
    int o2 = r2.x & 0xFFFF, p2 = (r2.x >> 16) & 0x3F;
    int o3 = r3.x & 0xFFFF, p3 = (r3.x >> 16) & 0x3F;
    float x0 = __uint_as_float(r0.y) * h1[o0 * WSZ + i16];   // 64B/group, L2-hit
    float x1 = __uint_as_float(r1.y) * h1[o1 * WSZ + i16];
    float x2 = __uint_as_float(r2.y) * h1[o2 * WSZ + i16];
    float x3 = __uint_as_float(r3.y) * h1[o3 * WSZ + i16];
    const float* wp0 = w2s + (p0 * WSZ + i16) * 12;
    const float* wp1 = w2s + (p1 * WSZ + i16) * 12;
    const float* wp2 = w2s + (p2 * WSZ + i16) * 12;
    const float* wp3 = w2s + (p3 * WSZ + i16) * 12;
#pragma unroll
    for (int c = 0; c < CC; ++c)
      t[c] += (x0 * wp0[c] + x1 * wp1[c]) + (x2 * wp2[c] + x3 * wp3[c]);
  }
  for (; e < end; e += 4) {
    uint2 r = recs[e];
    int o = r.x & 0xFFFF, p = (r.x >> 16) & 0x3F;
    float x = __uint_as_float(r.y) * h1[o * WSZ + i16];
    const float* wp = w2s + (p * WSZ + i16) * 12;
#pragma unroll
    for (int c = 0; c < CC; ++c) t[c] += x * wp[c];
  }
  // reduce over all 64 lanes (16 i-partials x 4 groups) per class
#pragma unroll
  for (int c = 0; c < CC; ++c) {
    float v = t[c];
    v += __shfl_xor(v, 1, 64);
    v += __shfl_xor(v, 2, 64);
    v += __shfl_xor(v, 4, 64);
    v += __shfl_xor(v, 8, 64);
    v += __shfl_xor(v, 16, 64);
    v += __shfl_xor(v, 32, 64);
    t[c] = v;
  }
  if (lane == 0) {
#pragma unroll
    for (int c = 0; c < CC; ++c) out[wid * CC + c] = t[c] + bias2[c];
  }
}

// ---------------- launcher ----------------
extern "C" void kernel_launch(void* const* d_in, const int* in_sizes, int n_in,
                              void* d_out, int out_size, void* d_ws, size_t ws_size,
                              hipStream_t stream) {
  const float* emb = (const float*)d_in[0];
  const float* w1  = (const float*)d_in[1];
  const float* b1  = (const float*)d_in[2];
  const float* w2  = (const float*)d_in[3];
  const float* b2  = (const float*)d_in[4];
  const float* ev  = (const float*)d_in[5];
  const int*   es  = (const int*)d_in[6];
  const int*   ep  = (const int*)d_in[7];
  const int*   eo  = (const int*)d_in[8];
  float* out = (float*)d_out;

  char* ws = (char*)d_ws;
  size_t off = 0;
  auto alloc = [&](size_t bytes) -> void* {
    void* p = ws + off;
    off = (off + bytes + 255) & ~(size_t)255;
    return p;
  };
  __hip_bfloat16* Bt  = (__hip_bfloat16*)alloc((size_t)NCP * DD * 2);  //   2 MB
  __hip_bfloat16* Hb  = (__hip_bfloat16*)alloc((size_t)NN * NC * 2);   // 52.8 MB
  float* h1   = (float*)alloc((size_t)NN * WSZ * 4);                   //  3.2 MB
  uint2* recs = (uint2*)alloc((size_t)EE * 8);                         // 25.6 MB
  int* counts = (int*)alloc((size_t)NN * 4);
  int* offs   = (int*)alloc((size_t)(NN + 1) * 4);
  int* ptr    = (int*)alloc((size_t)(NN + 1) * 4);
  int* bptr   = (int*)alloc((size_t)NBK * 4);
  int* part   = (int*)alloc((size_t)NBUSED * 4);
  int* bbase  = (int*)alloc((size_t)NBUSED * 4);
  // tmp aliases Hb (dead until k_gemm)
  uint2* tmp = (uint2*)Hb;

  hipMemsetAsync(counts, 0, (size_t)NN * 4, stream);

  k_bt_hist <<<16500, 256, 0, stream>>>(w1, Bt, es, counts);
  k_part    <<<NBUSED, 256, 0, stream>>>(counts, part);
  k_scan2   <<<1,      64, 0, stream>>>(part, bbase, bptr, offs);
  k_offs    <<<NBUSED,1024, 0, stream>>>(counts, bbase, offs, ptr);
  k_bucket  <<<(EE + MEDG - 1) / MEDG, 256, 0, stream>>>(es, ep, eo, ev, bptr, tmp);
  dim3 sg(NBUSED, SBPB);
  k_scatter2<<<sg,    256, 0, stream>>>(tmp, offs, ptr, recs);
  k_gemm    <<<8 * MPX * NNT, 256, 0, stream>>>(emb, Bt, Hb);   // 1960 blocks
  k_agg1    <<<12500, 256, 0, stream>>>(recs, offs, Hb, b1, h1);
  k_agg2f   <<<12500, 256, 0, stream>>>(recs, offs, h1, w2, b2, out);
}

// Round 3
// 876.134 us; speedup vs baseline: 1.4367x; 1.1925x over previous
//
#include <hip/hip_runtime.h>
#include <hip/hip_bf16.h>
#include <stdint.h>

// Problem constants
#define NN 50000            // nodes
#define RR 33               // relations
#define EE 3200000          // edges
#define DD 1600             // emb dim
#define WSZ 16              // weights_size
#define CC 10               // classes
#define NC (RR*WSZ)         // 528 columns of H
#define NCP 640             // Bt padded rows (5 * 128 column tiles)

// Bucketed-scatter params
#define NBK 64              // bucket slots (49 used)
#define BSH 10              // bucket = s >> 10  (1024 nodes/bucket)
#define NBUSED ((NN + (1<<BSH) - 1) >> BSH)   // 49
#define MEDG 4096           // edges staged per block in pass A
#define NHB ((EE + MEDG - 1) / MEDG)          // 782 histogram/bucket blocks

typedef __attribute__((ext_vector_type(8))) short bfrag;   // 8 bf16 = 4 VGPRs
typedef __attribute__((ext_vector_type(4))) float f32x4;

__device__ __forceinline__ unsigned short f2bf(float f) {
  union { float f; unsigned u; } v; v.f = f;
  unsigned r = v.u + 0x7FFF + ((v.u >> 16) & 1);   // RNE, inputs are finite
  return (unsigned short)(r >> 16);
}
__device__ __forceinline__ float bf2f(unsigned short h) {
  union { unsigned u; float f; } v; v.u = ((unsigned)h) << 16;
  return v.f;
}
// pack two fp32 -> two bf16 (round-to-nearest via +0x8000 bias; ~1 ulp max)
__device__ __forceinline__ unsigned pack2bf(float a, float b) {
  unsigned ua = __float_as_uint(a) + 0x8000u;
  unsigned ub = __float_as_uint(b) + 0x8000u;
  return (ua >> 16) | (ub & 0xFFFF0000u);
}

// ------ 1) fused: build B^T bf16 + per-block LDS bucket histogram -------------
// Global atomics: <=49 per histogram block (was 1 per edge -> cross-XCD bounce).
__global__ __launch_bounds__(256) void k_bt_hist(const float* __restrict__ w1,
                                                 __hip_bfloat16* __restrict__ bt,
                                                 const int* __restrict__ es,
                                                 int* __restrict__ bsz) {
  __shared__ int lh[NBK];
  int b = blockIdx.x;
  if (b < 4000) {
    int idx = b * 256 + threadIdx.x;                   // NCP*DD = 1,024,000 exact
    int n = idx / DD, k = idx - n * DD;
    float v = 0.f;
    if (n < NC) {
      int r = n >> 4, o = n & 15;
      v = w1[((size_t)r * DD + k) * WSZ + o];
    }
    *reinterpret_cast<unsigned short*>(&bt[idx]) = f2bf(v);
  } else {
    int tid = threadIdx.x;
    for (int i = tid; i < NBK; i += 256) lh[i] = 0;
    __syncthreads();
    int e0 = (b - 4000) * MEDG;
    int n = EE - e0; if (n > MEDG) n = MEDG;
    for (int i = tid; i < n; i += 256)
      atomicAdd(&lh[es[e0 + i] >> BSH], 1);
    __syncthreads();
    if (tid < NBK && lh[tid]) atomicAdd(&bsz[tid], lh[tid]);
  }
}

// ------ 2) scan 64 bucket sizes (one wave) -> bases + bucket cursors ----------
__global__ __launch_bounds__(64) void k_bscan(const int* __restrict__ bsz,
                                              int* __restrict__ bbase,
                                              int* __restrict__ bptr,
                                              int* __restrict__ offs) {
  int t = threadIdx.x;
  int v = bsz[t];                                      // unused slots are 0
  int incl = v;
#pragma unroll
  for (int off = 1; off < 64; off <<= 1) {
    int x = __shfl_up(incl, off, 64);
    if (t >= off) incl += x;
  }
  int excl = incl - v;
  bbase[t] = excl;
  bptr[t] = excl;
  if (t == 63) offs[NN] = EE;
}

// ------ 3) LDS-staged bucket binning (block reserves ~49 atomics total) -------
__global__ __launch_bounds__(256) void k_bucket(const int* __restrict__ es,
                                                const int* __restrict__ ep,
                                                const int* __restrict__ eo,
                                                const float* __restrict__ ev,
                                                int* __restrict__ bptr,
                                                uint2* __restrict__ tmp) {
  __shared__ int lhist[NBK];
  __shared__ int lofs[NBK];
  __shared__ int lcur[NBK];
  __shared__ int lbase[NBK];
  __shared__ uint2 stage[MEDG];
  __shared__ unsigned char sbk[MEDG];
  int tid = threadIdx.x;
  int e0 = blockIdx.x * MEDG;
  int n = EE - e0; if (n > MEDG) n = MEDG;
  for (int i = tid; i < NBK; i += 256) lhist[i] = 0;
  __syncthreads();
  for (int i = tid; i < n; i += 256)
    atomicAdd(&lhist[es[e0 + i] >> BSH], 1);
  __syncthreads();
  if (tid == 0) {
    int run = 0;
    for (int b = 0; b < NBK; ++b) { lofs[b] = run; run += lhist[b]; }
  }
  __syncthreads();
  if (tid < NBK) {
    lcur[tid] = lofs[tid];
    lbase[tid] = lhist[tid] ? atomicAdd(&bptr[tid], lhist[tid]) : 0;
  }
  __syncthreads();
  for (int i = tid; i < n; i += 256) {
    int s = es[e0 + i];
    int b = s >> BSH;
    int pos = atomicAdd(&lcur[b], 1);
    uint2 r;
    r.x = (unsigned)eo[e0 + i] | ((unsigned)ep[e0 + i] << 16)
        | ((unsigned)(s & 1023) << 22);
    r.y = __float_as_uint(ev[e0 + i]);
    stage[pos] = r;
    sbk[pos] = (unsigned char)b;
  }
  __syncthreads();
  for (int i = tid; i < n; i += 256) {                 // grouped -> ~sequential writes
    int b = sbk[i];
    tmp[lbase[b] + (i - lofs[b])] = stage[i];
  }
}

// ------ 4) per-bucket CSR build: LDS count + scan + LDS-cursor scatter --------
// One block per bucket (1024 node slots). Zero per-edge global atomics.
__global__ __launch_bounds__(1024) void k_csr(const uint2* __restrict__ tmp,
                                              const int* __restrict__ bbase,
                                              const int* __restrict__ bsz,
                                              int* __restrict__ offs,
                                              uint2* __restrict__ recs) {
  __shared__ int cnt[1024];
  __shared__ int sptr[1024];
  int b = blockIdx.x, t = threadIdx.x;                 // NBUSED blocks
  int base = bbase[b], size = bsz[b];
  cnt[t] = 0;
  __syncthreads();
  for (int i = t; i < size; i += 1024) {
    uint2 r = tmp[base + i];
    atomicAdd(&cnt[r.x >> 22], 1);                     // LDS atomic
  }
  __syncthreads();
  int v = cnt[t];
  __syncthreads();
  for (int off = 1; off < 1024; off <<= 1) {           // Hillis-Steele inclusive
    int x = (t >= off) ? cnt[t - off] : 0;
    __syncthreads();
    cnt[t] += x;
    __syncthreads();
  }
  int excl = cnt[t] - v;
  int node = (b << BSH) + t;
  if (node < NN) offs[node] = base + excl;
  sptr[t] = excl;
  __syncthreads();
  for (int i = t; i < size; i += 1024) {
    uint2 r = tmp[base + i];
    int pos = base + atomicAdd(&sptr[r.x >> 22], 1);   // LDS cursor
    recs[pos] = r;                                     // within ~512KB window: L2
  }
}

// ---------------- 5) GEMM: Hb = emb(fp32, fused convert) @ B, bf16 out --------
// Measured-good structure: 84 VGPR / 30% occ / ~219us. XCD swizzle +
// bank-swizzled LDS + 2-deep A prefetch crossing raw s_barrier. NNT=5.
#define BM 128
#define BN 128
#define BK 32
#define NMT 391              // m-tiles
#define NNT 5                // n-tiles
#define MPX 49               // m-strips per XCD (8*49 >= 391)
#define KIT (DD / BK)        // 50 K-iterations

// fine barrier: drain LDS + the 2 oldest vm ops (the B DMAs); leave the 8
// newer A prefetch loads in flight across the barrier.
#define BAR_FINE() asm volatile("s_waitcnt vmcnt(8) lgkmcnt(0)\n\ts_barrier" ::: "memory")

__global__ __launch_bounds__(256) void k_gemm(const float* __restrict__ A,
                                              const __hip_bfloat16* __restrict__ Bt,
                                              __hip_bfloat16* __restrict__ Hb) {
  __shared__ __align__(16) __hip_bfloat16 As[2][BM * BK];   // 8 KB each
  __shared__ __align__(16) __hip_bfloat16 Bs[2][BN * BK];   // 8 KB each
  int tid  = threadIdx.x;
  int wave = tid >> 6, lane = tid & 63;

  // XCD-aware swizzle: L%8 = XCD; per XCD a contiguous band of m-strips,
  // 5 n-tiles of a strip adjacent -> A strip served by ONE L2.
  int L = blockIdx.x;
  int xcd = L & 7;
  int r = L >> 3;
  int lm = r / NNT, nt = r - lm * NNT;
  int mt = xcd * MPX + lm;
  if (mt >= NMT) return;                // 5 no-op blocks (before any barrier)
  int m0 = mt * BM, n0 = nt * BN;

  int wm = (wave >> 1) * 64, wn = (wave & 1) * 64;       // 2x2 wave quadrants
  int ld = lane & 15, quad = lane >> 4;

  bool nact[4];
#pragma unroll
  for (int ni = 0; ni < 4; ++ni) nact[ni] = (n0 + wn + ni * 16) < NC;

  // ---- staging thread roles ----
  size_t rowAg[2];  int kcA[2];  int wofsA[2];           // A: load + swizzled LDS write
  size_t srcB[2];                                        // B: swizzled DMA source
#pragma unroll
  for (int j = 0; j < 2; ++j) {
    int idx = j * 256 + tid;
    int lrow = idx >> 2, kq = idx & 3;
    kcA[j] = kq * 8;
    int grow = m0 + lrow; if (grow > NN - 1) grow = NN - 1;
    rowAg[j] = (size_t)grow * DD;
    wofsA[j] = lrow * BK + ((kq + ((lrow >> 1) & 3)) & 3) * 8;   // XOR chunk swizzle
    int lcol = idx >> 2, pc = idx & 3;
    int kqsrc = (pc - ((lcol >> 1) & 3)) & 3;            // inverse swizzle on source
    srcB[j] = (size_t)(n0 + lcol) * DD + kqsrc * 8;
  }
  // fragment read offsets (swizzle term is mi/ni-invariant: (x+16)>>1 = x>>1+8)
  int swA = ((wm + ld) >> 1) & 3;
  int swB = ((wn + ld) >> 1) & 3;
  int rchA = ((quad + swA) & 3) * 8;
  int rchB = ((quad + swB) & 3) * 8;

  auto dmaB = [&](int k0, __hip_bfloat16* dst) {
#pragma unroll
    for (int j = 0; j < 2; ++j) {
      const __hip_bfloat16* gp = Bt + srcB[j] + k0;
      __builtin_amdgcn_global_load_lds(
          (const __attribute__((address_space(1))) void*)gp,
          (__attribute__((address_space(3))) void*)(dst + ((size_t)j * 256 + tid) * 8),
          16, 0, 0);
    }
  };
  float4 va[2][2][2];
  auto loadA = [&](int k0, int slot) {
#pragma unroll
    for (int j = 0; j < 2; ++j) {
      const float4* gp = (const float4*)(A + rowAg[j] + k0 + kcA[j]);
      va[slot][j][0] = gp[0]; va[slot][j][1] = gp[1];
    }
  };
  auto packA = [&](int slot, __hip_bfloat16* dst) {
#pragma unroll
    for (int j = 0; j < 2; ++j) {
      uint4 w;
      w.x = pack2bf(va[slot][j][0].x, va[slot][j][0].y);
      w.y = pack2bf(va[slot][j][0].z, va[slot][j][0].w);
      w.z = pack2bf(va[slot][j][1].x, va[slot][j][1].y);
      w.w = pack2bf(va[slot][j][1].z, va[slot][j][1].w);
      *reinterpret_cast<uint4*>(dst + wofsA[j]) = w;
    }
  };

  f32x4 acc[4][4] = {};
  auto mfmaTile = [&](const __hip_bfloat16* as, const __hip_bfloat16* bs) {
    bfrag af[4], bf[4];
#pragma unroll
    for (int mi = 0; mi < 4; ++mi)
      af[mi] = *(const bfrag*)(as + (wm + mi * 16 + ld) * BK + rchA);
#pragma unroll
    for (int ni = 0; ni < 4; ++ni)
      if (nact[ni])
        bf[ni] = *(const bfrag*)(bs + (wn + ni * 16 + ld) * BK + rchB);
#pragma unroll
    for (int mi = 0; mi < 4; ++mi)
#pragma unroll
      for (int ni = 0; ni < 4; ++ni)
        if (nact[ni])
          acc[mi][ni] = __builtin_amdgcn_mfma_f32_16x16x32_bf16(af[mi], bf[ni],
                                                                acc[mi][ni], 0, 0, 0);
  };

  // ---- prologue: T0 staged, T1 loads in regs ----
  loadA(0, 0);
  dmaB(0, Bs[0]);
  packA(0, As[0]);
  loadA(BK, 1);
  __syncthreads();

  // ---- main loop: it = 0..KIT-3 (48 iters), full 2-deep pipeline ----
#pragma unroll 2
  for (int it = 0; it < KIT - 2; ++it) {
    int buf = it & 1, nbuf = buf ^ 1;
    int k0 = it * BK;
    dmaB(k0 + BK, Bs[nbuf]);                 // oldest vm ops this iter
    __builtin_amdgcn_sched_barrier(0);       // keep DMA before A loads in vmcnt order
    loadA(k0 + 2 * BK, buf);                 // 8 loads that CROSS the barrier
    mfmaTile(As[buf], Bs[buf]);
    packA(nbuf, As[nbuf]);                   // consumes loads issued LAST iter
    BAR_FINE();                              // vmcnt(8): B done, A prefetch in flight
  }
  // ---- it = KIT-2 (48): no A issue; full drain barrier ----
  {
    int buf = (KIT - 2) & 1, nbuf = buf ^ 1;
    dmaB((KIT - 1) * BK, Bs[nbuf]);
    mfmaTile(As[buf], Bs[buf]);
    packA(nbuf, As[nbuf]);
    __syncthreads();
  }
  // ---- it = KIT-1 (49): compute only ----
  mfmaTile(As[(KIT - 1) & 1], Bs[(KIT - 1) & 1]);

  // ---- epilogue ----
#pragma unroll
  for (int mi = 0; mi < 4; ++mi)
#pragma unroll
    for (int ni = 0; ni < 4; ++ni) {
      int col = n0 + wn + ni * 16 + ld;
      if (col >= NC) continue;
#pragma unroll
      for (int r2 = 0; r2 < 4; ++r2) {
        int row = m0 + wm + mi * 16 + quad * 4 + r2;     // C/D: col=lane&15, row=quad*4+reg
        if (row < NN)
          *reinterpret_cast<unsigned short*>(&Hb[(size_t)row * NC + col]) =
              f2bf(acc[mi][ni][r2]);
      }
    }
}

// ---------------- 6) layer-1 aggregation: one wave per destination node -------
// 4 gather chains in flight per 16-lane group (latency-bound loop, MLP x4)
__global__ __launch_bounds__(256) void k_agg1(const uint2* __restrict__ recs,
                                              const int* __restrict__ offs,
                                              const __hip_bfloat16* __restrict__ Hb,
                                              const float* __restrict__ bias1,
                                              float* __restrict__ h1) {
  int wid  = (blockIdx.x * 256 + threadIdx.x) >> 6;      // exactly NN waves
  int lane = threadIdx.x & 63;
  int grp = lane >> 4, c = lane & 15;
  int beg = offs[wid], end = offs[wid + 1];
  float acc = 0.f;
  int e = beg + grp;
  for (; e + 12 < end; e += 16) {                        // 4 independent chains
    uint2 r0 = recs[e];
    uint2 r1 = recs[e + 4];
    uint2 r2 = recs[e + 8];
    uint2 r3 = recs[e + 12];
    int o0 = r0.x & 0xFFFF, p0 = (r0.x >> 16) & 0x3F;
    int o1 = r1.x & 0xFFFF, p1 = (r1.x >> 16) & 0x3F;
    int o2 = r2.x & 0xFFFF, p2 = (r2.x >> 16) & 0x3F;
    int o3 = r3.x & 0xFFFF, p3 = (r3.x >> 16) & 0x3F;
    unsigned short h0 = *reinterpret_cast<const unsigned short*>(
        &Hb[(size_t)o0 * NC + p0 * WSZ + c]);
    unsigned short h1v = *reinterpret_cast<const unsigned short*>(
        &Hb[(size_t)o1 * NC + p1 * WSZ + c]);
    unsigned short h2v = *reinterpret_cast<const unsigned short*>(
        &Hb[(size_t)o2 * NC + p2 * WSZ + c]);
    unsigned short h3v = *reinterpret_cast<const unsigned short*>(
        &Hb[(size_t)o3 * NC + p3 * WSZ + c]);
    acc += __uint_as_float(r0.y) * bf2f(h0);
    acc += __uint_as_float(r1.y) * bf2f(h1v);
    acc += __uint_as_float(r2.y) * bf2f(h2v);
    acc += __uint_as_float(r3.y) * bf2f(h3v);
  }
  for (; e < end; e += 4) {
    uint2 r = recs[e];
    int o = r.x & 0xFFFF, p = (r.x >> 16) & 0x3F;
    unsigned short h = *reinterpret_cast<const unsigned short*>(
        &Hb[(size_t)o * NC + p * WSZ + c]);
    acc += __uint_as_float(r.y) * bf2f(h);
  }
  acc += __shfl_xor(acc, 16, 64);
  acc += __shfl_xor(acc, 32, 64);
  if (lane < 16) h1[wid * WSZ + c] = fmaxf(acc + bias1[c], 0.f);
}

// ---------------- 7) fused layer-2 projection + aggregation -------------------
// out[s,c] = b2[c] + sum_e val * sum_i h1[o,i] * w2[p,i,c]
// h1 is 3.2 MB -> L2-resident gathers; H2 never materialized.
__global__ __launch_bounds__(256) void k_agg2f(const uint2* __restrict__ recs,
                                               const int* __restrict__ offs,
                                               const float* __restrict__ h1,
                                               const float* __restrict__ w2,
                                               const float* __restrict__ bias2,
                                               float* __restrict__ out) {
  __shared__ float w2s[RR * WSZ * 12];                   // stride 12: b128-aligned rows
  for (int i = threadIdx.x; i < RR * WSZ * CC; i += 256) {
    int pi = i / CC, c = i - pi * CC;
    w2s[pi * 12 + c] = w2[i];
  }
  __syncthreads();
  int wid  = (blockIdx.x * 256 + threadIdx.x) >> 6;      // exactly NN waves
  int lane = threadIdx.x & 63;
  int grp = lane >> 4, i16 = lane & 15;                  // lane owns i = i16
  int beg = offs[wid], end = offs[wid + 1];
  float t[CC] = {};
  int e = beg + grp;
  for (; e + 12 < end; e += 16) {                        // 4 independent chains
    uint2 r0 = recs[e];
    uint2 r1 = recs[e + 4];
    uint2 r2 = recs[e + 8];
    uint2 r3 = recs[e + 12];
    int o0 = r0.x & 0xFFFF, p0 = (r0.x >> 16) & 0x3F;
    int o1 = r1.x & 0xFFFF, p1 = (r1.x >> 16) & 0x3F;
    int o2 = r2.x & 0xFFFF, p2 = (r2.x >> 16) & 0x3F;
    int o3 = r3.x & 0xFFFF, p3 = (r3.x >> 16) & 0x3F;
    float x0 = __uint_as_float(r0.y) * h1[o0 * WSZ + i16];   // 64B/group, L2-hit
    float x1 = __uint_as_float(r1.y) * h1[o1 * WSZ + i16];
    float x2 = __uint_as_float(r2.y) * h1[o2 * WSZ + i16];
    float x3 = __uint_as_float(r3.y) * h1[o3 * WSZ + i16];
    const float* wp0 = w2s + (p0 * WSZ + i16) * 12;
    const float* wp1 = w2s + (p1 * WSZ + i16) * 12;
    const float* wp2 = w2s + (p2 * WSZ + i16) * 12;
    const float* wp3 = w2s + (p3 * WSZ + i16) * 12;
#pragma unroll
    for (int c = 0; c < CC; ++c)
      t[c] += (x0 * wp0[c] + x1 * wp1[c]) + (x2 * wp2[c] + x3 * wp3[c]);
  }
  for (; e < end; e += 4) {
    uint2 r = recs[e];
    int o = r.x & 0xFFFF, p = (r.x >> 16) & 0x3F;
    float x = __uint_as_float(r.y) * h1[o * WSZ + i16];
    const float* wp = w2s + (p * WSZ + i16) * 12;
#pragma unroll
    for (int c = 0; c < CC; ++c) t[c] += x * wp[c];
  }
  // reduce over all 64 lanes (16 i-partials x 4 groups) per class
#pragma unroll
  for (int c = 0; c < CC; ++c) {
    float v = t[c];
    v += __shfl_xor(v, 1, 64);
    v += __shfl_xor(v, 2, 64);
    v += __shfl_xor(v, 4, 64);
    v += __shfl_xor(v, 8, 64);
    v += __shfl_xor(v, 16, 64);
    v += __shfl_xor(v, 32, 64);
    t[c] = v;
  }
  if (lane == 0) {
#pragma unroll
    for (int c = 0; c < CC; ++c) out[wid * CC + c] = t[c] + bias2[c];
  }
}

// ---------------- launcher ----------------
extern "C" void kernel_launch(void* const* d_in, const int* in_sizes, int n_in,
                              void* d_out, int out_size, void* d_ws, size_t ws_size,
                              hipStream_t stream) {
  const float* emb = (const float*)d_in[0];
  const float* w1  = (const float*)d_in[1];
  const float* b1  = (const float*)d_in[2];
  const float* w2  = (const float*)d_in[3];
  const float* b2  = (const float*)d_in[4];
  const float* ev  = (const float*)d_in[5];
  const int*   es  = (const int*)d_in[6];
  const int*   ep  = (const int*)d_in[7];
  const int*   eo  = (const int*)d_in[8];
  float* out = (float*)d_out;

  char* ws = (char*)d_ws;
  size_t off = 0;
  auto alloc = [&](size_t bytes) -> void* {
    void* p = ws + off;
    off = (off + bytes + 255) & ~(size_t)255;
    return p;
  };
  __hip_bfloat16* Bt  = (__hip_bfloat16*)alloc((size_t)NCP * DD * 2);  //   2 MB
  __hip_bfloat16* Hb  = (__hip_bfloat16*)alloc((size_t)NN * NC * 2);   // 52.8 MB
  float* h1   = (float*)alloc((size_t)NN * WSZ * 4);                   //  3.2 MB
  uint2* recs = (uint2*)alloc((size_t)EE * 8);                         // 25.6 MB
  int* offs   = (int*)alloc((size_t)(NN + 1) * 4);
  int* bsz    = (int*)alloc((size_t)NBK * 4);
  int* bbase  = (int*)alloc((size_t)NBK * 4);
  int* bptr   = (int*)alloc((size_t)NBK * 4);
  // tmp aliases Hb (dead until k_gemm)
  uint2* tmp = (uint2*)Hb;

  hipMemsetAsync(bsz, 0, (size_t)NBK * 4, stream);

  k_bt_hist <<<4000 + NHB, 256, 0, stream>>>(w1, Bt, es, bsz);
  k_bscan   <<<1,       64, 0, stream>>>(bsz, bbase, bptr, offs);
  k_bucket  <<<NHB,    256, 0, stream>>>(es, ep, eo, ev, bptr, tmp);
  k_csr     <<<NBUSED,1024, 0, stream>>>(tmp, bbase, bsz, offs, recs);
  k_gemm    <<<8 * MPX * NNT, 256, 0, stream>>>(emb, Bt, Hb);   // 1960 blocks
  k_agg1    <<<12500, 256, 0, stream>>>(recs, offs, Hb, b1, h1);
  k_agg2f   <<<12500, 256, 0, stream>>>(recs, offs, h1, w2, b2, out);
}

// Round 5
// 813.449 us; speedup vs baseline: 1.5474x; 1.0771x over previous
//
#include <hip/hip_runtime.h>
#include <hip/hip_bf16.h>
#include <stdint.h>

// Problem constants
#define NN 50000            // nodes
#define RR 33               // relations
#define EE 3200000          // edges
#define DD 1600             // emb dim
#define WSZ 16              // weights_size
#define CC 10               // classes
#define NC (RR*WSZ)         // 528 columns of H
#define NCP 640             // Bt padded rows (5 * 128 column tiles)

// Bucketed-scatter params
#define NBK 256             // bucket slots (196 used)
#define BSH 8               // bucket = s >> 8  (256 nodes/bucket)
#define NBUSED ((NN + (1<<BSH) - 1) >> BSH)   // 196
#define MEDG 4096           // edges staged per block in pass A
#define NHB ((EE + MEDG - 1) / MEDG)          // 782 histogram/bucket blocks

typedef __attribute__((ext_vector_type(8))) short bfrag;   // 8 bf16 = 4 VGPRs
typedef __attribute__((ext_vector_type(4))) float f32x4;

__device__ __forceinline__ unsigned short f2bf(float f) {
  union { float f; unsigned u; } v; v.f = f;
  unsigned r = v.u + 0x7FFF + ((v.u >> 16) & 1);   // RNE, inputs are finite
  return (unsigned short)(r >> 16);
}
__device__ __forceinline__ float bf2f(unsigned short h) {
  union { unsigned u; float f; } v; v.u = ((unsigned)h) << 16;
  return v.f;
}
// pack two fp32 -> two bf16 (round-to-nearest via +0x8000 bias; ~1 ulp max)
__device__ __forceinline__ unsigned pack2bf(float a, float b) {
  unsigned ua = __float_as_uint(a) + 0x8000u;
  unsigned ub = __float_as_uint(b) + 0x8000u;
  return (ua >> 16) | (ub & 0xFFFF0000u);
}

// ------ 1) fused: build B^T bf16 + per-block LDS bucket histogram -------------
__global__ __launch_bounds__(256) void k_bt_hist(const float* __restrict__ w1,
                                                 __hip_bfloat16* __restrict__ bt,
                                                 const int* __restrict__ es,
                                                 int* __restrict__ bsz) {
  __shared__ int lh[NBK];
  int b = blockIdx.x;
  if (b < 4000) {
    int idx = b * 256 + threadIdx.x;                   // NCP*DD = 1,024,000 exact
    int n = idx / DD, k = idx - n * DD;
    float v = 0.f;
    if (n < NC) {
      int r = n >> 4, o = n & 15;
      v = w1[((size_t)r * DD + k) * WSZ + o];
    }
    *reinterpret_cast<unsigned short*>(&bt[idx]) = f2bf(v);
  } else {
    int tid = threadIdx.x;
    lh[tid] = 0;                                       // NBK == blockDim
    __syncthreads();
    int e0 = (b - 4000) * MEDG;
    int n = EE - e0; if (n > MEDG) n = MEDG;
    for (int i = tid; i < n; i += 256)
      atomicAdd(&lh[es[e0 + i] >> BSH], 1);
    __syncthreads();
    if (lh[tid]) atomicAdd(&bsz[tid], lh[tid]);
  }
}

// ------ 2) scan 256 bucket sizes (one block) -> bases + bucket cursors --------
__global__ __launch_bounds__(256) void k_bscan(const int* __restrict__ bsz,
                                               int* __restrict__ bbase,
                                               int* __restrict__ bptr,
                                               int* __restrict__ offs) {
  __shared__ int sc[NBK];
  int t = threadIdx.x;
  int v = bsz[t];                                      // unused slots are 0
  sc[t] = v;
  __syncthreads();
  for (int off = 1; off < NBK; off <<= 1) {
    int x = (t >= off) ? sc[t - off] : 0;
    __syncthreads();
    sc[t] += x;
    __syncthreads();
  }
  int excl = sc[t] - v;
  bbase[t] = excl;
  bptr[t] = excl;
  if (t == NBK - 1) offs[NN] = EE;
}

// ------ 3) LDS-staged bucket binning (block reserves <=196 atomics total) -----
__global__ __launch_bounds__(256) void k_bucket(const int* __restrict__ es,
                                                const int* __restrict__ ep,
                                                const int* __restrict__ eo,
                                                const float* __restrict__ ev,
                                                int* __restrict__ bptr,
                                                uint2* __restrict__ tmp) {
  __shared__ int lhist[NBK];
  __shared__ int lofs[NBK];
  __shared__ int lcur[NBK];
  __shared__ int lbase[NBK];
  __shared__ uint2 stage[MEDG];
  __shared__ unsigned char sbk[MEDG];
  int tid = threadIdx.x;
  int e0 = blockIdx.x * MEDG;
  int n = EE - e0; if (n > MEDG) n = MEDG;
  lhist[tid] = 0;                                      // NBK == blockDim
  __syncthreads();
  for (int i = tid; i < n; i += 256)
    atomicAdd(&lhist[es[e0 + i] >> BSH], 1);
  __syncthreads();
  // 256-wide exclusive scan of lhist -> lofs
  lofs[tid] = lhist[tid];
  __syncthreads();
  for (int off = 1; off < NBK; off <<= 1) {
    int x = (tid >= off) ? lofs[tid - off] : 0;
    __syncthreads();
    lofs[tid] += x;
    __syncthreads();
  }
  int excl = lofs[tid] - lhist[tid];
  lofs[tid] = excl;                                    // own-slot rewrite, safe
  lcur[tid] = excl;
  lbase[tid] = lhist[tid] ? atomicAdd(&bptr[tid], lhist[tid]) : 0;
  __syncthreads();
  for (int i = tid; i < n; i += 256) {
    int s = es[e0 + i];
    int b = s >> BSH;
    int pos = atomicAdd(&lcur[b], 1);
    uint2 r;
    r.x = (unsigned)eo[e0 + i] | ((unsigned)ep[e0 + i] << 16)
        | ((unsigned)(s & ((1 << BSH) - 1)) << 22);
    r.y = __float_as_uint(ev[e0 + i]);
    stage[pos] = r;
    sbk[pos] = (unsigned char)b;                       // 196 <= 255 fits
  }
  __syncthreads();
  for (int i = tid; i < n; i += 256) {                 // grouped -> ~sequential writes
    int b = sbk[i];
    tmp[lbase[b] + (i - lofs[b])] = stage[i];
  }
}

// ------ 4) per-bucket CSR build: LDS count + scan + LDS-cursor scatter --------
// 196 blocks x 1024 threads (was 49 -> 4x the CUs). Zero per-edge global atomics.
__global__ __launch_bounds__(1024) void k_csr(const uint2* __restrict__ tmp,
                                              const int* __restrict__ bbase,
                                              const int* __restrict__ bsz,
                                              int* __restrict__ offs,
                                              uint2* __restrict__ recs) {
  __shared__ int cnt[1 << BSH];
  __shared__ int sptr[1 << BSH];
  int b = blockIdx.x, t = threadIdx.x;                 // NBUSED blocks
  int base = bbase[b], size = bsz[b];
  if (t < (1 << BSH)) cnt[t] = 0;
  __syncthreads();
  for (int i = t; i < size; i += 1024)
    atomicAdd(&cnt[tmp[base + i].x >> 22], 1);         // LDS atomic
  __syncthreads();
  int v = (t < (1 << BSH)) ? cnt[t] : 0;
  __syncthreads();
  for (int off = 1; off < (1 << BSH); off <<= 1) {     // Hillis-Steele inclusive
    int x = (t >= off && t < (1 << BSH)) ? cnt[t - off] : 0;
    __syncthreads();
    if (t < (1 << BSH)) cnt[t] += x;
    __syncthreads();
  }
  if (t < (1 << BSH)) {
    int excl = cnt[t] - v;
    int node = (b << BSH) + t;
    if (node < NN) offs[node] = base + excl;
    sptr[t] = excl;
  }
  __syncthreads();
  for (int i = t; i < size; i += 1024) {
    uint2 r = tmp[base + i];
    int pos = base + atomicAdd(&sptr[r.x >> 22], 1);   // LDS cursor
    recs[pos] = r;                                     // within ~128KB window: L2
  }
}

// ---------------- 5) GEMM: Hb = emb(fp32, fused convert) @ B, bf16 out --------
// Measured-good structure: 84 VGPR / 30% occ / ~220us. XCD swizzle +
// bank-swizzled LDS + 2-deep A prefetch crossing raw s_barrier. NNT=5.
#define BM 128
#define BN 128
#define BK 32
#define NMT 391              // m-tiles
#define NNT 5                // n-tiles
#define MPX 49               // m-strips per XCD (8*49 >= 391)
#define KIT (DD / BK)        // 50 K-iterations

// fine barrier: drain LDS + the 2 oldest vm ops (the B DMAs); leave the 8
// newer A prefetch loads in flight across the barrier.
#define BAR_FINE() asm volatile("s_waitcnt vmcnt(8) lgkmcnt(0)\n\ts_barrier" ::: "memory")

__global__ __launch_bounds__(256) void k_gemm(const float* __restrict__ A,
                                              const __hip_bfloat16* __restrict__ Bt,
                                              __hip_bfloat16* __restrict__ Hb) {
  __shared__ __align__(16) __hip_bfloat16 As[2][BM * BK];   // 8 KB each
  __shared__ __align__(16) __hip_bfloat16 Bs[2][BN * BK];   // 8 KB each
  int tid  = threadIdx.x;
  int wave = tid >> 6, lane = tid & 63;

  // XCD-aware swizzle: L%8 = XCD; per XCD a contiguous band of m-strips,
  // 5 n-tiles of a strip adjacent -> A strip served by ONE L2.
  int L = blockIdx.x;
  int xcd = L & 7;
  int r = L >> 3;
  int lm = r / NNT, nt = r - lm * NNT;
  int mt = xcd * MPX + lm;
  if (mt >= NMT) return;                // 5 no-op blocks (before any barrier)
  int m0 = mt * BM, n0 = nt * BN;

  int wm = (wave >> 1) * 64, wn = (wave & 1) * 64;       // 2x2 wave quadrants
  int ld = lane & 15, quad = lane >> 4;

  bool nact[4];
#pragma unroll
  for (int ni = 0; ni < 4; ++ni) nact[ni] = (n0 + wn + ni * 16) < NC;

  // ---- staging thread roles ----
  size_t rowAg[2];  int kcA[2];  int wofsA[2];           // A: load + swizzled LDS write
  size_t srcB[2];                                        // B: swizzled DMA source
#pragma unroll
  for (int j = 0; j < 2; ++j) {
    int idx = j * 256 + tid;
    int lrow = idx >> 2, kq = idx & 3;
    kcA[j] = kq * 8;
    int grow = m0 + lrow; if (grow > NN - 1) grow = NN - 1;
    rowAg[j] = (size_t)grow * DD;
    wofsA[j] = lrow * BK + ((kq + ((lrow >> 1) & 3)) & 3) * 8;   // XOR chunk swizzle
    int lcol = idx >> 2, pc = idx & 3;
    int kqsrc = (pc - ((lcol >> 1) & 3)) & 3;            // inverse swizzle on source
    srcB[j] = (size_t)(n0 + lcol) * DD + kqsrc * 8;
  }
  // fragment read offsets (swizzle term is mi/ni-invariant: (x+16)>>1 = x>>1+8)
  int swA = ((wm + ld) >> 1) & 3;
  int swB = ((wn + ld) >> 1) & 3;
  int rchA = ((quad + swA) & 3) * 8;
  int rchB = ((quad + swB) & 3) * 8;

  auto dmaB = [&](int k0, __hip_bfloat16* dst) {
#pragma unroll
    for (int j = 0; j < 2; ++j) {
      const __hip_bfloat16* gp = Bt + srcB[j] + k0;
      __builtin_amdgcn_global_load_lds(
          (const __attribute__((address_space(1))) void*)gp,
          (__attribute__((address_space(3))) void*)(dst + ((size_t)j * 256 + tid) * 8),
          16, 0, 0);
    }
  };
  float4 va[2][2][2];
  auto loadA = [&](int k0, int slot) {
#pragma unroll
    for (int j = 0; j < 2; ++j) {
      const float4* gp = (const float4*)(A + rowAg[j] + k0 + kcA[j]);
      va[slot][j][0] = gp[0]; va[slot][j][1] = gp[1];
    }
  };
  auto packA = [&](int slot, __hip_bfloat16* dst) {
#pragma unroll
    for (int j = 0; j < 2; ++j) {
      uint4 w;
      w.x = pack2bf(va[slot][j][0].x, va[slot][j][0].y);
      w.y = pack2bf(va[slot][j][0].z, va[slot][j][0].w);
      w.z = pack2bf(va[slot][j][1].x, va[slot][j][1].y);
      w.w = pack2bf(va[slot][j][1].z, va[slot][j][1].w);
      *reinterpret_cast<uint4*>(dst + wofsA[j]) = w;
    }
  };

  f32x4 acc[4][4] = {};
  auto mfmaTile = [&](const __hip_bfloat16* as, const __hip_bfloat16* bs) {
    bfrag af[4], bf[4];
#pragma unroll
    for (int mi = 0; mi < 4; ++mi)
      af[mi] = *(const bfrag*)(as + (wm + mi * 16 + ld) * BK + rchA);
#pragma unroll
    for (int ni = 0; ni < 4; ++ni)
      if (nact[ni])
        bf[ni] = *(const bfrag*)(bs + (wn + ni * 16 + ld) * BK + rchB);
#pragma unroll
    for (int mi = 0; mi < 4; ++mi)
#pragma unroll
      for (int ni = 0; ni < 4; ++ni)
        if (nact[ni])
          acc[mi][ni] = __builtin_amdgcn_mfma_f32_16x16x32_bf16(af[mi], bf[ni],
                                                                acc[mi][ni], 0, 0, 0);
  };

  // ---- prologue: T0 staged, T1 loads in regs ----
  loadA(0, 0);
  dmaB(0, Bs[0]);
  packA(0, As[0]);
  loadA(BK, 1);
  __syncthreads();

  // ---- main loop: it = 0..KIT-3 (48 iters), full 2-deep pipeline ----
#pragma unroll 2
  for (int it = 0; it < KIT - 2; ++it) {
    int buf = it & 1, nbuf = buf ^ 1;
    int k0 = it * BK;
    dmaB(k0 + BK, Bs[nbuf]);                 // oldest vm ops this iter
    __builtin_amdgcn_sched_barrier(0);       // keep DMA before A loads in vmcnt order
    loadA(k0 + 2 * BK, buf);                 // 8 loads that CROSS the barrier
    mfmaTile(As[buf], Bs[buf]);
    packA(nbuf, As[nbuf]);                   // consumes loads issued LAST iter
    BAR_FINE();                              // vmcnt(8): B done, A prefetch in flight
  }
  // ---- it = KIT-2 (48): no A issue; full drain barrier ----
  {
    int buf = (KIT - 2) & 1, nbuf = buf ^ 1;
    dmaB((KIT - 1) * BK, Bs[nbuf]);
    mfmaTile(As[buf], Bs[buf]);
    packA(nbuf, As[nbuf]);
    __syncthreads();
  }
  // ---- it = KIT-1 (49): compute only ----
  mfmaTile(As[(KIT - 1) & 1], Bs[(KIT - 1) & 1]);

  // ---- epilogue ----
#pragma unroll
  for (int mi = 0; mi < 4; ++mi)
#pragma unroll
    for (int ni = 0; ni < 4; ++ni) {
      int col = n0 + wn + ni * 16 + ld;
      if (col >= NC) continue;
#pragma unroll
      for (int r2 = 0; r2 < 4; ++r2) {
        int row = m0 + wm + mi * 16 + quad * 4 + r2;     // C/D: col=lane&15, row=quad*4+reg
        if (row < NN)
          *reinterpret_cast<unsigned short*>(&Hb[(size_t)row * NC + col]) =
              f2bf(acc[mi][ni][r2]);
      }
    }
}

// ---------------- 6) layer-1 aggregation: one wave per destination node -------
// 8 gather chains in flight per 16-lane group + 4-deep middle tier.
__global__ __launch_bounds__(256) void k_agg1(const uint2* __restrict__ recs,
                                              const int* __restrict__ offs,
                                              const __hip_bfloat16* __restrict__ Hb,
                                              const float* __restrict__ bias1,
                                              float* __restrict__ h1) {
  int wid  = (blockIdx.x * 256 + threadIdx.x) >> 6;      // exactly NN waves
  int lane = threadIdx.x & 63;
  int grp = lane >> 4, c = lane & 15;
  int beg = offs[wid], end = offs[wid + 1];
  float acc = 0.f;
  int e = beg + grp;
  for (; e + 28 < end; e += 32) {                        // 8 independent chains
    uint2 rr[8]; unsigned short hh[8];
#pragma unroll
    for (int q = 0; q < 8; ++q) rr[q] = recs[e + 4 * q];
#pragma unroll
    for (int q = 0; q < 8; ++q) {
      int o = rr[q].x & 0xFFFF, p = (rr[q].x >> 16) & 0x3F;
      hh[q] = *reinterpret_cast<const unsigned short*>(
          &Hb[(size_t)o * NC + p * WSZ + c]);
    }
#pragma unroll
    for (int q = 0; q < 8; ++q) acc += __uint_as_float(rr[q].y) * bf2f(hh[q]);
  }
  if (e + 12 < end) {                                    // one 4-deep step
    uint2 rr[4]; unsigned short hh[4];
#pragma unroll
    for (int q = 0; q < 4; ++q) rr[q] = recs[e + 4 * q];
#pragma unroll
    for (int q = 0; q < 4; ++q) {
      int o = rr[q].x & 0xFFFF, p = (rr[q].x >> 16) & 0x3F;
      hh[q] = *reinterpret_cast<const unsigned short*>(
          &Hb[(size_t)o * NC + p * WSZ + c]);
    }
#pragma unroll
    for (int q = 0; q < 4; ++q) acc += __uint_as_float(rr[q].y) * bf2f(hh[q]);
    e += 16;
  }
  for (; e < end; e += 4) {
    uint2 r = recs[e];
    int o = r.x & 0xFFFF, p = (r.x >> 16) & 0x3F;
    unsigned short h = *reinterpret_cast<const unsigned short*>(
        &Hb[(size_t)o * NC + p * WSZ + c]);
    acc += __uint_as_float(r.y) * bf2f(h);
  }
  acc += __shfl_xor(acc, 16, 64);
  acc += __shfl_xor(acc, 32, 64);
  if (lane < 16) h1[wid * WSZ + c] = fmaxf(acc + bias1[c], 0.f);
}

// ---------------- 7) fused layer-2 projection + aggregation -------------------
// out[s,c] = b2[c] + sum_e val * sum_i h1[o,i] * w2[p,i,c]
// h1 is 3.2 MB -> L2-resident gathers; H2 never materialized. 8-deep MLP.
__global__ __launch_bounds__(256) void k_agg2f(const uint2* __restrict__ recs,
                                               const int* __restrict__ offs,
                                               const float* __restrict__ h1,
                                               const float* __restrict__ w2,
                                               const float* __restrict__ bias2,
                                               float* __restrict__ out) {
  __shared__ float w2s[RR * WSZ * 12];                   // stride 12: b128-aligned rows
  for (int i = threadIdx.x; i < RR * WSZ * CC; i += 256) {
    int pi = i / CC, c = i - pi * CC;
    w2s[pi * 12 + c] = w2[i];
  }
  __syncthreads();
  int wid  = (blockIdx.x * 256 + threadIdx.x) >> 6;      // exactly NN waves
  int lane = threadIdx.x & 63;
  int grp = lane >> 4, i16 = lane & 15;                  // lane owns i = i16
  int beg = offs[wid], end = offs[wid + 1];
  float t[CC] = {};
  int e = beg + grp;
  for (; e + 28 < end; e += 32) {                        // 8 independent chains
    uint2 rr[8]; float xx[8]; int pp[8];
#pragma unroll
    for (int q = 0; q < 8; ++q) rr[q] = recs[e + 4 * q];
#pragma unroll
    for (int q = 0; q < 8; ++q) {
      int o = rr[q].x & 0xFFFF;
      pp[q] = (rr[q].x >> 16) & 0x3F;
      xx[q] = __uint_as_float(rr[q].y) * h1[o * WSZ + i16];   // L2-resident
    }
#pragma unroll
    for (int q = 0; q < 8; ++q) {
      const float* wp = w2s + (pp[q] * WSZ + i16) * 12;
#pragma unroll
      for (int c = 0; c < CC; ++c) t[c] += xx[q] * wp[c];
    }
  }
  if (e + 12 < end) {                                    // one 4-deep step
    uint2 rr[4]; float xx[4]; int pp[4];
#pragma unroll
    for (int q = 0; q < 4; ++q) rr[q] = recs[e + 4 * q];
#pragma unroll
    for (int q = 0; q < 4; ++q) {
      int o = rr[q].x & 0xFFFF;
      pp[q] = (rr[q].x >> 16) & 0x3F;
      xx[q] = __uint_as_float(rr[q].y) * h1[o * WSZ + i16];
    }
#pragma unroll
    for (int q = 0; q < 4; ++q) {
      const float* wp = w2s + (pp[q] * WSZ + i16) * 12;
#pragma unroll
      for (int c = 0; c < CC; ++c) t[c] += xx[q] * wp[c];
    }
    e += 16;
  }
  for (; e < end; e += 4) {
    uint2 r = recs[e];
    int o = r.x & 0xFFFF, p = (r.x >> 16) & 0x3F;
    float x = __uint_as_float(r.y) * h1[o * WSZ + i16];
    const float* wp = w2s + (p * WSZ + i16) * 12;
#pragma unroll
    for (int c = 0; c < CC; ++c) t[c] += x * wp[c];
  }
  // reduce over all 64 lanes (16 i-partials x 4 groups) per class
#pragma unroll
  for (int c = 0; c < CC; ++c) {
    float v = t[c];
    v += __shfl_xor(v, 1, 64);
    v += __shfl_xor(v, 2, 64);
    v += __shfl_xor(v, 4, 64);
    v += __shfl_xor(v, 8, 64);
    v += __shfl_xor(v, 16, 64);
    v += __shfl_xor(v, 32, 64);
    t[c] = v;
  }
  if (lane == 0) {
#pragma unroll
    for (int c = 0; c < CC; ++c) out[wid * CC + c] = t[c] + bias2[c];
  }
}

// ---------------- launcher ----------------
extern "C" void kernel_launch(void* const* d_in, const int* in_sizes, int n_in,
                              void* d_out, int out_size, void* d_ws, size_t ws_size,
                              hipStream_t stream) {
  const float* emb = (const float*)d_in[0];
  const float* w1  = (const float*)d_in[1];
  const float* b1  = (const float*)d_in[2];
  const float* w2  = (const float*)d_in[3];
  const float* b2  = (const float*)d_in[4];
  const float* ev  = (const float*)d_in[5];
  const int*   es  = (const int*)d_in[6];
  const int*   ep  = (const int*)d_in[7];
  const int*   eo  = (const int*)d_in[8];
  float* out = (float*)d_out;

  char* ws = (char*)d_ws;
  size_t off = 0;
  auto alloc = [&](size_t bytes) -> void* {
    void* p = ws + off;
    off = (off + bytes + 255) & ~(size_t)255;
    return p;
  };
  __hip_bfloat16* Bt  = (__hip_bfloat16*)alloc((size_t)NCP * DD * 2);  //   2 MB
  __hip_bfloat16* Hb  = (__hip_bfloat16*)alloc((size_t)NN * NC * 2);   // 52.8 MB
  float* h1   = (float*)alloc((size_t)NN * WSZ * 4);                   //  3.2 MB
  uint2* recs = (uint2*)alloc((size_t)EE * 8);                         // 25.6 MB
  int* offs   = (int*)alloc((size_t)(NN + 1) * 4);
  int* bsz    = (int*)alloc((size_t)NBK * 4);
  int* bbase  = (int*)alloc((size_t)NBK * 4);
  int* bptr   = (int*)alloc((size_t)NBK * 4);
  // tmp aliases Hb (dead until k_gemm)
  uint2* tmp = (uint2*)Hb;

  hipMemsetAsync(bsz, 0, (size_t)NBK * 4, stream);

  k_bt_hist <<<4000 + NHB, 256, 0, stream>>>(w1, Bt, es, bsz);
  k_bscan   <<<1,      256, 0, stream>>>(bsz, bbase, bptr, offs);
  k_bucket  <<<NHB,    256, 0, stream>>>(es, ep, eo, ev, bptr, tmp);
  k_csr     <<<NBUSED,1024, 0, stream>>>(tmp, bbase, bsz, offs, recs);
  k_gemm    <<<8 * MPX * NNT, 256, 0, stream>>>(emb, Bt, Hb);   // 1960 blocks
  k_agg1    <<<12500, 256, 0, stream>>>(recs, offs, Hb, b1, h1);
  k_agg2f   <<<12500, 256, 0, stream>>>(recs, offs, h1, w2, b2, out);
}